// Round 11
// baseline (20.694 us; speedup 1.0000x reference)
//
#include <hip/hip_runtime.h>
#include <hip/hip_bf16.h>

typedef short short8 __attribute__((ext_vector_type(8)));
typedef float f32x4 __attribute__((ext_vector_type(4)));

union FragAB { unsigned long long l[2]; int i[4]; short8 v; };

// Round-11: LDS-traffic-minimal wave mapping.
//
// Swapped-operand formulation: D[p=(b,f), j] = sum_i A[p,i] * B[i,j]
//   A[p,i] = bf16(x[b, sx, i, f])            (Xts rows, k-contiguous)
//   B[i,j] = T[j,i] = wfor[255 + diag - j + i]
//   wfor[q] = krow[q] for q in [0,255], 0 elsewhere (zero-pad = triangular
//   mask AND the diagonal roll-by-one, which switches divisor to j+1-diag).
// Four shifted copies of wfor (copy s holds wfor shifted +s) make every
// lane's 8-element window 8-byte aligned -> B-frag = 2x ds_read_b64.
//
// Wave (wp,par) owns 32 p-rows (m=0..1, rows 32wp+16m) x 128 j-cols as the
// 8 parity-interleaved 16-col groups G = 2g+par (g=0..7, j0 = 32g+16par).
// Group g is active at K-steps st <= g and completes at st == g:
//   - per K-step only 2 A-b128 reads, shared by all active groups
//     (A-LDS traffic per CU: ~23k cyc in round 10 -> ~3k cyc here)
//   - every wave: identical 8 steps, 72 MFMA, one 2-store burst per step
//     -> uniform store stream + perfect wave balance by construction.
__global__ __launch_bounds__(256, 3)
void k_fused(const float* __restrict__ x,     // [16,8,256,16]
             const float* __restrict__ kern,  // [4,8,8,256]
             float* __restrict__ out)         // [16,4,8,8,256,16]
{
    __shared__ __align__(16) ushort Xts[64 * 264];   // [p][k], row 528 B
    __shared__ __align__(8)  ushort wforL[4][336];   // [shift][q]
    __shared__ float rtab[256];

    const int blk = blockIdx.x;             // 0..1023
    const int hy = blk & 31;                // h*8 + sy
    const int sx = (blk >> 5) & 7;
    const int nt = blk >> 8;                // p-quarter (b-quad)
    const int h = hy >> 3, sy = hy & 7;
    const int diag = (sx == sy) ? 1 : 0;
    const int t = threadIdx.x;

    // ---- wfor shift-copies (bf16) ----
    {
        const float* krow = kern + ((h * 8 + sx) * 8 + sy) * 256;
        #pragma unroll
        for (int s = 0; s < 4; ++s) {
            #pragma unroll
            for (int pass = 0; pass < 2; ++pass) {
                int q = t + pass * 256;
                if (q < 336) {
                    int src = q - s;
                    float v = (src >= 0 && src < 256) ? krow[src] : 0.0f;
                    __hip_bfloat16 hv = __float2bfloat16(v);
                    wforL[s][q] = reinterpret_cast<ushort&>(hv);
                }
            }
        }
    }
    // ---- reciprocal table for this block's diag ----
    {
        int denom = t + 1 - diag;
        rtab[t] = (denom > 0) ? (1.0f / (float)denom) : 0.0f;
    }
    // ---- stage + transpose x quarter-slice -> Xts: Xts[bl*16+f][k] ----
    {
        const float4* xbase = reinterpret_cast<const float4*>(x);
        #pragma unroll
        for (int it = 0; it < 8; ++it) {
            int id = it * 256 + t;              // 0..2047
            int fq = id & 3;
            int k2 = (id >> 2) & 127;
            int bl = id >> 9;                   // local b 0..3
            const float4* rowp = xbase + ((size_t)((nt * 4 + bl) * 8 + sx)) * 1024;
            float4 a = rowp[(2 * k2) * 4 + fq];
            float4 cq = rowp[(2 * k2 + 1) * 4 + fq];
            #pragma unroll
            for (int e = 0; e < 4; ++e) {
                float va = (&a.x)[e], vb = (&cq.x)[e];
                __hip_bfloat16 ha = __float2bfloat16(va);
                __hip_bfloat16 hb = __float2bfloat16(vb);
                uint u = (uint)reinterpret_cast<ushort&>(ha) |
                         ((uint)reinterpret_cast<ushort&>(hb) << 16);
                int row = bl * 16 + fq * 4 + e;
                *reinterpret_cast<uint*>(reinterpret_cast<char*>(Xts) + row * 528 + k2 * 4) = u;
            }
        }
    }
    __syncthreads();

    const int lane = t & 63, wid = t >> 6;
    const int laneM = lane & 15, laneG = lane >> 4;
    const int wp  = wid >> 1;                   // p-half (rows 32wp..32wp+31)
    const int par = wid & 1;                    // j-group parity

    const char* XtsB = reinterpret_cast<const char*>(Xts);
    const char* WB = reinterpret_cast<const char*>(wforL);
    const int abyte = (32 * wp + laneM) * 528 + laneG * 16;

    // B window for group G=2g+par at step kc: elems w00 - 32g + kc + e,
    // w00 = 255 + diag - 16par - laneM + 8laneG  (G=par base).
    const int w00 = 255 + diag - 16 * par - laneM + 8 * laneG;
    const int s = (laneM - diag + 1 - 16 * par) & 3;   // (w00+s) % 4 == 0
    const int bBw = s * 674 + 2 * w00;          // byte base (incl. +s shift)

    f32x4 acc[8][2];
    #pragma unroll
    for (int g = 0; g < 8; ++g)
        #pragma unroll
        for (int m = 0; m < 2; ++m)
            acc[g][m] = (f32x4){0.0f, 0.0f, 0.0f, 0.0f};

    #pragma unroll
    for (int st = 0; st < 8; ++st) {
        const int kc = 32 * st;
        FragAB af[2];
        #pragma unroll
        for (int m = 0; m < 2; ++m) {
            const int4 raw = *reinterpret_cast<const int4*>(
                XtsB + abyte + m * 8448 + kc * 2);
            af[m].i[0] = raw.x; af[m].i[1] = raw.y;
            af[m].i[2] = raw.z; af[m].i[3] = raw.w;
        }
        #pragma unroll
        for (int g = 0; g < 8; ++g) {
            if (g >= st) {                      // group active this step
                FragAB bf;
                const char* p = WB + bBw - 64 * g + kc * 2;
                bf.l[0] = *reinterpret_cast<const unsigned long long*>(p);
                bf.l[1] = *reinterpret_cast<const unsigned long long*>(p + 8);
                #pragma unroll
                for (int m = 0; m < 2; ++m)
                    acc[g][m] = __builtin_amdgcn_mfma_f32_16x16x32_bf16(
                        af[m].v, bf.v, acc[g][m], 0, 0, 0);
            }
            if (g == st) {                      // group completes -> store now
                const int j = 32 * g + 16 * par + laneM;
                const float rt = rtab[j];
                #pragma unroll
                for (int m = 0; m < 2; ++m) {
                    const int b_ = nt * 4 + 2 * wp + m;
                    float* dst = out
                        + (((size_t)(b_ * 4 + h) * 8 + sx) * 8 + sy) * 4096
                        + (size_t)j * 16 + laneG * 4;
                    f32x4 v = acc[g][m] * rt;
                    __builtin_nontemporal_store(v, reinterpret_cast<f32x4*>(dst));
                }
            }
        }
    }
}

extern "C" void kernel_launch(void* const* d_in, const int* in_sizes, int n_in,
                              void* d_out, int out_size, void* d_ws, size_t ws_size,
                              hipStream_t stream) {
    const float* x    = (const float*)d_in[0];   // [16,8,256,16]
    const float* kern = (const float*)d_in[1];   // [4,8,8,256]
    float* out = (float*)d_out;                  // [16,4,8,8,256,16]

    k_fused<<<1024, 256, 0, stream>>>(x, kern, out);
}